// Round 4
// baseline (348.933 us; speedup 1.0000x reference)
//
#include <hip/hip_runtime.h>

#define LEAKY 0.2f

typedef __attribute__((ext_vector_type(8))) short short8;   // 8 bf16 (MFMA A/B frag)
typedef __attribute__((ext_vector_type(4))) float floatx4;  // MFMA C/D frag
typedef __attribute__((ext_vector_type(8))) unsigned short ushort8_t;

__device__ __forceinline__ float bf2f(unsigned short u) {
    return __uint_as_float(((unsigned)u) << 16);
}
__device__ __forceinline__ unsigned short f2bf(float f) {
    unsigned u = __float_as_uint(f);
    unsigned r = (u + 0x7fffu + ((u >> 16) & 1u)) >> 16;  // RNE
    return (unsigned short)r;
}
__device__ __forceinline__ float relu_nan(float v) { return v < 0.0f ? 0.0f : v; }

// async global->LDS, 16 B per lane (dest = wave-uniform base + lane*16; SRC is per-lane)
__device__ __forceinline__ void gload_lds16(const void* g, void* l) {
    __builtin_amdgcn_global_load_lds((const __attribute__((address_space(1))) void*)g,
                                     (__attribute__((address_space(3))) void*)l, 16, 0, 0);
}

// ---------- K_fill (ws-too-small diagnosis: out filled with ws MB) ----------
__global__ void k_fill(float* __restrict__ p, float val, int n) {
    int i = blockIdx.x * blockDim.x + threadIdx.x;
    if (i < n) p[i] = val;
}

// ---------- K_prep: cvt X, weight transposes, score-weight matvec, edge histogram ----------
// cnt must be zeroed (hipMemsetAsync) before this kernel.
__global__ void k_prep(const float* __restrict__ X, unsigned short* __restrict__ Xb,
                       const float* __restrict__ Wn, unsigned short* __restrict__ WnT,
                       const float* __restrict__ W1, unsigned short* __restrict__ W1T,
                       const float* __restrict__ W2, unsigned short* __restrict__ W2T,
                       const float* __restrict__ Asrc, const float* __restrict__ Adst,
                       float* __restrict__ Wsd,
                       const int* __restrict__ dst, int* __restrict__ cnt,
                       int N, int E) {
    const int gs = gridDim.x * blockDim.x;
    const int tid = blockIdx.x * blockDim.x + threadIdx.x;
    for (int i = tid; i < N * 32; i += gs) {
        float4 v = ((const float4*)X)[i];
        ushort4 o;
        o.x = f2bf(v.x); o.y = f2bf(v.y); o.z = f2bf(v.z); o.w = f2bf(v.w);
        ((ushort4*)Xb)[i] = o;
    }
    for (int i = tid; i < 256 * 128; i += gs) {   // WnT[col][k], col=head*64+d
        int col = i >> 7, k = i & 127;
        int head = col >> 6, d = col & 63;
        WnT[i] = f2bf(Wn[(size_t)head * 8192 + (size_t)k * 64 + d]);
    }
    for (int i = tid; i < 256 * 256; i += gs) {   // W1T[n][k] = W1[k][n]
        int n = i >> 8, k = i & 255;
        W1T[i] = f2bf(W1[(size_t)k * 256 + n]);
    }
    for (int i = tid; i < 128 * 256; i += gs) {   // W2T[n][k] = W2[k][n]
        int n = i >> 8, k = i & 255;
        W2T[i] = f2bf(W2[(size_t)k * 128 + n]);
    }
    // Wsd[j][k]: j<4 -> Wn[h]@a_src[h], j>=4 -> Wn[h]@a_dst[h]  (h=j&3)
    for (int i = tid; i < 8 * 128; i += gs) {
        int j = i >> 7, k = i & 127, h = j & 3;
        const float* av = (j < 4 ? Asrc : Adst) + h * 64;
        const float* wrow = Wn + (size_t)h * 8192 + (size_t)k * 64;
        float acc = 0.0f;
        for (int d = 0; d < 64; ++d) acc += wrow[d] * av[d];
        Wsd[i] = acc;
    }
    for (int i = tid; i < E; i += gs) atomicAdd(cnt + dst[i], 1);  // fused histogram
}

// ---------- K_scores: s_src/s_dst = Xb @ Wsd^T  (per-node matvec, [N,8]) ----------
__global__ __launch_bounds__(256) void k_scores(
    const unsigned short* __restrict__ Xb, const float* __restrict__ Wsd,
    float* __restrict__ s_src, float* __restrict__ s_dst, int N) {
    const int gs = gridDim.x * 256;
    const int tid = blockIdx.x * 256 + threadIdx.x;
    for (int i = tid; i < N * 8; i += gs) {
        const int n = i >> 3, j = i & 7;
        const unsigned short* xr = Xb + (size_t)n * 128;
        const float* wr = Wsd + j * 128;
        float acc = 0.0f;
        for (int k = 0; k < 128; k += 8) {
            ushort8_t xv = *(const ushort8_t*)(xr + k);
#pragma unroll
            for (int u = 0; u < 8; ++u) acc = fmaf(bf2f(xv[u]), wr[k + u], acc);
        }
        if (j < 4) s_src[n * 4 + j] = acc;
        else       s_dst[n * 4 + (j - 4)] = acc;
    }
}

// ---------- K3a/b/c: two-level exclusive scan (proven version) ----------
__global__ __launch_bounds__(256) void k_scan1(
    const int* __restrict__ cnt, int* __restrict__ rowptr, int* __restrict__ bsum, int N) {
    __shared__ int wtot[4];
    const int lane = threadIdx.x & 63, wave = threadIdx.x >> 6;
    const int i = blockIdx.x * 256 + threadIdx.x;
    int v = (i < N) ? cnt[i] : 0;
    int x = v;
    for (int off = 1; off < 64; off <<= 1) {
        int y = __shfl_up(x, off, 64);
        if (lane >= off) x += y;
    }
    if (lane == 63) wtot[wave] = x;
    __syncthreads();
    int wo = 0;
    for (int wv = 0; wv < wave; ++wv) wo += wtot[wv];
    if (i < N) rowptr[i] = wo + x - v;
    if (threadIdx.x == 255) bsum[blockIdx.x] = wo + x;
}
__global__ void k_scan2(int* __restrict__ bsum, int nb) {
    const int lane = threadIdx.x;
    int carry = 0;
    for (int base = 0; base < nb; base += 64) {
        int i = base + lane;
        int v = (i < nb) ? bsum[i] : 0;
        int x = v;
        for (int off = 1; off < 64; off <<= 1) {
            int y = __shfl_up(x, off, 64);
            if (lane >= off) x += y;
        }
        if (i < nb) bsum[i] = carry + x - v;
        carry += __shfl(x, 63, 64);
    }
}
__global__ void k_scan3(int* __restrict__ rowptr, const int* __restrict__ bsum,
                        int* __restrict__ wcnt, int N, int E) {
    int i = blockIdx.x * blockDim.x + threadIdx.x;
    if (i < N) {
        int v = rowptr[i] + bsum[i >> 8];
        rowptr[i] = v;
        wcnt[i] = v;
    }
    if (i == N) rowptr[N] = E;
}

// ---------- K_scatter: src ids into CSR order + per-edge ex (4 heads, f32) + owner ----------
__global__ void k_scatter(const int* __restrict__ src, const int* __restrict__ dst,
                          int* __restrict__ wcnt,
                          const float* __restrict__ s_src, const float* __restrict__ s_dst,
                          int* __restrict__ esrc, float* __restrict__ ex4,
                          unsigned char* __restrict__ ownb, int E) {
    int e = blockIdx.x * blockDim.x + threadIdx.x;
    if (e < E) {
        const int s = src[e], d = dst[e];
        const int pos = atomicAdd(wcnt + d, 1);
        esrc[pos] = s;
        ownb[pos] = (unsigned char)(d & 15);
        const float4 ss = *(const float4*)(s_src + (size_t)s * 4);
        const float4 sd = *(const float4*)(s_dst + (size_t)d * 4);
        float4 o;
        float v;
        v = ss.x + sd.x; v = fmaxf(v, LEAKY * v); o.x = __expf(v);
        v = ss.y + sd.y; v = fmaxf(v, LEAKY * v); o.y = __expf(v);
        v = ss.z + sd.z; v = fmaxf(v, LEAKY * v); o.z = __expf(v);
        v = ss.w + sd.w; v = fmaxf(v, LEAKY * v); o.w = __expf(v);
        *(float4*)(ex4 + (size_t)pos * 4) = o;
    }
}

// ---------- K_agg: MFMA gather-aggregate + fused per-head Wn transform ----------
// One block = 16 consecutive dst rows (CSR edges contiguous). 4 waves = 4 heads.
// Per K-block of 32 edge slots: EX(16x32, hi/lo bf16) @ Xg(32x128).
// X rows are reg-staged and written TRANSPOSED into LDS XtT[dim=128][slotpair=16]
// (dword = slots 2s|2s+1 of one dim), so the MFMA B-frag is a plain contiguous
// ds_read_b128 (lane(g4,lm): dim-row dg*16+lm, slots g4*8..+7). No tr-read.
// Staggered write parity -> 2 lanes/bank (free, m136).
// Tail: acc(16x128) -> Cs (XOR-swizzled rows) -> 16 MFMA vs WnT -> relu*inv_den -> concat.
__global__ __launch_bounds__(256, 4) void k_agg(
    const unsigned short* __restrict__ Xb,
    const int* __restrict__ rowptr, const int* __restrict__ esrc,
    const float* __restrict__ ex4, const unsigned char* __restrict__ ownb,
    const unsigned short* __restrict__ WnT,
    unsigned short* __restrict__ concat, int N) {
    __shared__ unsigned XtT[128 * 16];           // [dim][slotpair] dwords, 8 KB
    __shared__ float exl[2][4][32];              // meta dbuf: ex per head
    __shared__ int sidl[2][32];
    __shared__ int ownl[2][32];
    __shared__ float denl[4][16];
    __shared__ unsigned short Cs[4][16 * 128];   // 16 KB, per-wave agg tile

    const int t = threadIdx.x;
    const int lane = t & 63;
    const int w = t >> 6;                // wave == head
    const int r0 = blockIdx.x * 16;
    const int r1 = min(r0 + 16, N);
    const int beg = rowptr[r0], end = rowptr[r1];
    const int nkb = (end - beg + 31) >> 5;

    const int r = lane & 15;             // A row / Cs row / transform row
    const int g4 = lane >> 4;            // k-partition (lane group)
    const int s2 = t & 15;               // staging slot-pair (0..15)
    const int dg8 = t >> 4;              // staging dim-group of 8 (0..15)

    floatx4 acc[8];
#pragma unroll
    for (int dg = 0; dg < 8; ++dg) acc[dg] = (floatx4){0, 0, 0, 0};
    float den = 0.0f;

    if (t < 32 && nkb > 0) {             // meta(0)
        int pos = beg + t;
        bool v = pos < end;
        int s = v ? esrc[pos] : 0;
        float4 e = v ? *(const float4*)(ex4 + (size_t)pos * 4) : (float4){0, 0, 0, 0};
        sidl[0][t] = s;
        ownl[0][t] = v ? (int)ownb[pos] : 255;
        exl[0][0][t] = e.x; exl[0][1][t] = e.y; exl[0][2][t] = e.z; exl[0][3][t] = e.w;
    }
    __syncthreads();

    for (int kb = 0; kb < nkb; ++kb) {
        const int mb = kb & 1;
        // ---- issue this K-block's gathers early (2 x 16B per thread) ----
        const int se = sidl[mb][2 * s2];
        const int so = sidl[mb][2 * s2 + 1];
        const ushort8_t xe = *(const ushort8_t*)(Xb + (size_t)se * 128 + dg8 * 8);
        const ushort8_t xo = *(const ushort8_t*)(Xb + (size_t)so * 128 + dg8 * 8);
        // ---- prefetch meta(kb+1) into regs ----
        int pf_sid = 0, pf_own = 255;
        float4 pf_ex = (float4){0, 0, 0, 0};
        const bool havepf = (t < 32) && (kb + 1 < nkb);
        if (havepf) {
            int pos = beg + (kb + 1) * 32 + t;
            if (pos < end) {
                pf_sid = esrc[pos];
                pf_ex = *(const float4*)(ex4 + (size_t)pos * 4);
                pf_own = ownb[pos];
            }
        }
        // ---- A-frags (hi/lo bf16 split of ex; den from exact f32) ----
        unsigned hiu[4], lou[4];
        {
            const float4 ea = *(const float4*)&exl[mb][w][g4 * 8];
            const float4 eb = *(const float4*)&exl[mb][w][g4 * 8 + 4];
            const int4 oa = *(const int4*)&ownl[mb][g4 * 8];
            const int4 ob = *(const int4*)&ownl[mb][g4 * 8 + 4];
            float ev[8];
            ev[0] = (oa.x == r) ? ea.x : 0.0f;
            ev[1] = (oa.y == r) ? ea.y : 0.0f;
            ev[2] = (oa.z == r) ? ea.z : 0.0f;
            ev[3] = (oa.w == r) ? ea.w : 0.0f;
            ev[4] = (ob.x == r) ? eb.x : 0.0f;
            ev[5] = (ob.y == r) ? eb.y : 0.0f;
            ev[6] = (ob.z == r) ? eb.z : 0.0f;
            ev[7] = (ob.w == r) ? eb.w : 0.0f;
#pragma unroll
            for (int j = 0; j < 8; ++j) den += ev[j];
#pragma unroll
            for (int jj = 0; jj < 4; ++jj) {
                unsigned h0 = f2bf(ev[2 * jj]), h1 = f2bf(ev[2 * jj + 1]);
                float l0 = ev[2 * jj] - bf2f((unsigned short)h0);
                float l1 = ev[2 * jj + 1] - bf2f((unsigned short)h1);
                hiu[jj] = h0 | (h1 << 16);
                lou[jj] = (unsigned)f2bf(l0) | ((unsigned)f2bf(l1) << 16);
            }
        }
        // ---- pack (even|odd slot per dword) + transposed LDS write ----
        unsigned outp[8];
        const unsigned* xeu = (const unsigned*)&xe;
        const unsigned* xou = (const unsigned*)&xo;
#pragma unroll
        for (int m2 = 0; m2 < 4; ++m2) {
            outp[2 * m2]     = (xeu[m2] & 0xffffu) | (xou[m2] << 16);
            outp[2 * m2 + 1] = (xeu[m2] >> 16) | (xou[m2] & 0xffff0000u);
        }
#pragma unroll
        for (int i = 0; i < 8; ++i) {
            const int js = (i + g4) & 7;     // parity stagger -> 2 lanes/bank
            XtT[(dg8 * 8 + js) * 16 + s2] = outp[js];
        }
        __syncthreads();                     // XtT(kb) visible to all waves
        // ---- B-frags (contiguous b128) + 16 MFMA ----
        union { short8 v; unsigned u[4]; } ahi, alo;
#pragma unroll
        for (int jj = 0; jj < 4; ++jj) { ahi.u[jj] = hiu[jj]; alo.u[jj] = lou[jj]; }
#pragma unroll
        for (int dg = 0; dg < 8; ++dg) {
            const short8 bfv = *(const short8*)((const unsigned short*)XtT +
                                                (size_t)(dg * 16 + r) * 32 + g4 * 8);
            acc[dg] = __builtin_amdgcn_mfma_f32_16x16x32_bf16(ahi.v, bfv, acc[dg], 0, 0, 0);
            acc[dg] = __builtin_amdgcn_mfma_f32_16x16x32_bf16(alo.v, bfv, acc[dg], 0, 0, 0);
        }
        // ---- publish meta(kb+1) ----
        if (havepf) {
            const int nb2 = (kb + 1) & 1;
            sidl[nb2][t] = pf_sid;
            ownl[nb2][t] = pf_own;
            exl[nb2][0][t] = pf_ex.x; exl[nb2][1][t] = pf_ex.y;
            exl[nb2][2][t] = pf_ex.z; exl[nb2][3][t] = pf_ex.w;
        }
        __syncthreads();                     // XtT free; meta(kb+1) visible
    }

    // den: reduce across the 4 k-partitions
    den += __shfl_xor(den, 16, 64);
    den += __shfl_xor(den, 32, 64);
    if (lane < 16) denl[w][lane] = den;

    // acc (C layout: row=g4*4+q, col=dg*16+r) -> Cs, XOR-swizzled rows
    unsigned short* cw = &Cs[w][0];
#pragma unroll
    for (int dg = 0; dg < 8; ++dg)
#pragma unroll
        for (int q = 0; q < 4; ++q) {
            int row = g4 * 4 + q;
            int cbyte = (dg * 16 + r) * 2;
            cw[(row * 256 + (cbyte ^ ((row & 7) << 4))) >> 1] = f2bf(acc[dg][q]);
        }
    __syncthreads();                         // Cs + denl visible (incl. cross-lane)

    // fused per-head transform: out16x64 = Cs(16x128) @ Wn[h](128x64)
    floatx4 acc2[4];
#pragma unroll
    for (int f = 0; f < 4; ++f) acc2[f] = (floatx4){0, 0, 0, 0};
#pragma unroll
    for (int kb2 = 0; kb2 < 4; ++kb2) {
        int abyte = r * 256 + ((kb2 * 64 + g4 * 16) ^ ((r & 7) << 4));
        short8 a2 = *(const short8*)((const char*)cw + abyte);
#pragma unroll
        for (int f = 0; f < 4; ++f) {
            short8 b2 = *(const short8*)(WnT +
                (size_t)(w * 64 + f * 16 + r) * 128 + kb2 * 32 + g4 * 8);
            acc2[f] = __builtin_amdgcn_mfma_f32_16x16x32_bf16(a2, b2, acc2[f], 0, 0, 0);
        }
    }

#pragma unroll
    for (int f = 0; f < 4; ++f)
#pragma unroll
        for (int q = 0; q < 4; ++q) {
            int row = g4 * 4 + q;
            int rn = r0 + row;
            if (rn < N) {
                float dv = denl[w][row];
                float inv = 1.0f / (dv > 0.0f ? dv : 1.0f);
                concat[(size_t)rn * 256 + w * 64 + f * 16 + r] =
                    f2bf(relu_nan(acc2[f][q]) * inv);
            }
        }
}

// ---------- K_gemm: tiled MFMA GEMM (MLP layers) ----------
// MODE 1: bf16 out, +bias, relu     (MLP layer 1 -> hidden)
// MODE 2: fp32 out, +bias           (MLP layer 2 -> final)
template <int K, int MODE>
__global__ __launch_bounds__(256) void k_gemm(
    const unsigned short* __restrict__ A, const unsigned short* __restrict__ BT,
    const float* __restrict__ bias, unsigned short* __restrict__ Cb,
    float* __restrict__ Cf, int N, int ldout) {
    __shared__ unsigned short As[128 * 32];
    __shared__ unsigned short Bs[128 * 32];
    const int t = threadIdx.x;
    const int lane = t & 63;
    const int w = t >> 6;
    const int wy = w >> 1, wx = w & 1;
    const int lm = lane & 15, quad = lane >> 4;
    const int row0 = blockIdx.x * 128;
    const int n0 = blockIdx.y * 128;
    const int srow = lane >> 2;
    const int sk = (lane & 3) * 8;

    floatx4 acc[4][4];
#pragma unroll
    for (int ni = 0; ni < 4; ++ni) {
        float b = bias[n0 + wx * 64 + ni * 16 + lm];
#pragma unroll
        for (int mi = 0; mi < 4; ++mi) acc[mi][ni] = (floatx4){b, b, b, b};
    }

    for (int k0 = 0; k0 < K; k0 += 32) {
#pragma unroll
        for (int p = 0; p < 2; ++p) {
            int tr = (p * 4 + w) * 16 + srow;
            int ga = row0 + tr; if (ga >= N) ga = N - 1;   // clamp (stores guarded)
            gload_lds16(A + (size_t)ga * K + k0 + sk,
                        (char*)As + (size_t)tr * 64 + sk * 2);
            gload_lds16(BT + (size_t)(n0 + tr) * K + k0 + sk,
                        (char*)Bs + (size_t)tr * 64 + sk * 2);
        }
        __syncthreads();
        short8 af[4], bfr[4];
#pragma unroll
        for (int mi = 0; mi < 4; ++mi)
            af[mi] = *(const short8*)(As + (size_t)(wy * 64 + mi * 16 + lm) * 32 + quad * 8);
#pragma unroll
        for (int ni = 0; ni < 4; ++ni)
            bfr[ni] = *(const short8*)(Bs + (size_t)(wx * 64 + ni * 16 + lm) * 32 + quad * 8);
#pragma unroll
        for (int mi = 0; mi < 4; ++mi)
#pragma unroll
            for (int ni = 0; ni < 4; ++ni)
                acc[mi][ni] = __builtin_amdgcn_mfma_f32_16x16x32_bf16(af[mi], bfr[ni], acc[mi][ni], 0, 0, 0);
        __syncthreads();
    }

#pragma unroll
    for (int mi = 0; mi < 4; ++mi)
#pragma unroll
        for (int ni = 0; ni < 4; ++ni)
#pragma unroll
            for (int q = 0; q < 4; ++q) {
                int r = row0 + wy * 64 + mi * 16 + quad * 4 + q;
                int c = n0 + wx * 64 + ni * 16 + lm;
                if (r < N) {
                    if (MODE == 1) Cb[(size_t)r * ldout + c] = f2bf(relu_nan(acc[mi][ni][q]));
                    else           Cf[(size_t)r * ldout + c] = acc[mi][ni][q];
                }
            }
}

extern "C" void kernel_launch(void* const* d_in, const int* in_sizes, int n_in,
                              void* d_out, int out_size, void* d_ws, size_t ws_size,
                              hipStream_t stream) {
    const float* X    = (const float*)d_in[0];
    const int* src    = (const int*)d_in[1];
    const int* dst    = (const int*)d_in[2];
    const float* Wn   = (const float*)d_in[3];
    const float* Asrc = (const float*)d_in[4];
    const float* Adst = (const float*)d_in[5];
    const float* W1   = (const float*)d_in[6];
    const float* b1   = (const float*)d_in[7];
    const float* W2   = (const float*)d_in[8];
    const float* b2   = (const float*)d_in[9];
    float* out = (float*)d_out;

    const int N = in_sizes[0] / 128;   // 50000
    const int E = in_sizes[1];         // 800000
    const int NBS = (N + 255) / 256;   // scan blocks
    const int NR = (N + 127) / 128;    // GEMM row tiles (MLP)
    const int NG = (N + 15) / 16;      // k_agg groups

    // ws layout (16B-aligned offsets), ~58 MB.
    size_t off = 0;
    char* w = (char*)d_ws;
    unsigned short* hid = (unsigned short*)(w + off);  off += (size_t)N * 256 * 2;  // MLP hidden
    unsigned short* Xb  = (unsigned short*)(w + off);  off += (size_t)N * 128 * 2;  // bf16 X
    float* s_src = (float*)(w + off);                  off += (size_t)N * 4 * 4;
    float* s_dst = (float*)(w + off);                  off += (size_t)N * 4 * 4;
    int* cnt     = (int*)(w + off);                    off += (size_t)N * 4;
    int* rowptr  = (int*)(w + off);                    off += ((size_t)(N + 1) * 4 + 15) & ~15ull;
    int* wcnt    = (int*)(w + off);                    off += (size_t)N * 4;
    int* bsum    = (int*)(w + off);                    off += ((size_t)NBS * 4 + 15) & ~15ull;
    int* esrc    = (int*)(w + off);                    off += (size_t)E * 4;
    float* ex4   = (float*)(w + off);                  off += (size_t)E * 4 * 4;
    unsigned char* ownb = (unsigned char*)(w + off);   off += ((size_t)E + 15) & ~15ull;
    unsigned short* W1T = (unsigned short*)(w + off);  off += 256 * 256 * 2;
    unsigned short* W2T = (unsigned short*)(w + off);  off += 128 * 256 * 2;
    unsigned short* WnT = (unsigned short*)(w + off);  off += 256 * 128 * 2;
    float* Wsd   = (float*)(w + off);                  off += 8 * 128 * 4;
    const size_t required = off;

    if (ws_size < required) {
        k_fill<<<dim3((out_size + 255) / 256), dim3(256), 0, stream>>>(
            out, (float)(ws_size >> 20), out_size);
        return;
    }

    // d_out staging: concat (bf16 [N,256]) from k_agg -> consumed by gemm1;
    // then final fp32 out overwrites it (concat dead after gemm1).
    unsigned short* concat = (unsigned short*)d_out;

    hipMemsetAsync(cnt, 0, (size_t)N * sizeof(int), stream);
    k_prep<<<dim3(2048), dim3(256), 0, stream>>>(X, Xb, Wn, WnT, W1, W1T, W2, W2T,
                                                 Asrc, Adst, Wsd, dst, cnt, N, E);
    k_scores<<<dim3((N * 8 + 255) / 256), dim3(256), 0, stream>>>(Xb, Wsd, s_src, s_dst, N);
    k_scan1<<<dim3(NBS), dim3(256), 0, stream>>>(cnt, rowptr, bsum, N);
    k_scan2<<<dim3(1), dim3(64), 0, stream>>>(bsum, NBS);
    k_scan3<<<dim3((N + 256) / 256), dim3(256), 0, stream>>>(rowptr, bsum, wcnt, N, E);
    k_scatter<<<dim3((E + 255) / 256), dim3(256), 0, stream>>>(src, dst, wcnt, s_src, s_dst,
                                                               esrc, ex4, ownb, E);
    k_agg<<<dim3(NG), dim3(256), 0, stream>>>(Xb, rowptr, esrc, ex4, ownb, WnT, concat, N);
    // layer 1: hidden = relu(concat @ W1 + b1)
    k_gemm<256, 1><<<dim3(NR, 2), dim3(256), 0, stream>>>(
        concat, W1T, b1, hid, nullptr, N, 256);
    // layer 2: out = hidden @ W2 + b2 -> fp32 into d_out
    k_gemm<256, 2><<<dim3(NR, 1), dim3(256), 0, stream>>>(
        hid, W2T, b2, nullptr, out, N, 128);
}

// Round 5
// 299.938 us; speedup vs baseline: 1.1634x; 1.1634x over previous
//
#include <hip/hip_runtime.h>

#define LEAKY 0.2f

typedef __attribute__((ext_vector_type(8))) short short8;   // 8 bf16 (MFMA A/B frag)
typedef __attribute__((ext_vector_type(4))) float floatx4;  // MFMA C/D frag
typedef __attribute__((ext_vector_type(8))) unsigned short ushort8_t;

__device__ __forceinline__ float bf2f(unsigned short u) {
    return __uint_as_float(((unsigned)u) << 16);
}
__device__ __forceinline__ unsigned short f2bf(float f) {
    unsigned u = __float_as_uint(f);
    unsigned r = (u + 0x7fffu + ((u >> 16) & 1u)) >> 16;  // RNE
    return (unsigned short)r;
}
__device__ __forceinline__ float relu_nan(float v) { return v < 0.0f ? 0.0f : v; }

// async global->LDS, 16 B per lane (dest = wave-uniform base + lane*16)
__device__ __forceinline__ void gload_lds16(const void* g, void* l) {
    __builtin_amdgcn_global_load_lds((const __attribute__((address_space(1))) void*)g,
                                     (__attribute__((address_space(3))) void*)l, 16, 0, 0);
}

// ---------- K_fill (ws-too-small diagnosis) ----------
__global__ void k_fill(float* __restrict__ p, float val, int n) {
    int i = blockIdx.x * blockDim.x + threadIdx.x;
    if (i < n) p[i] = val;
}

// ---------- K_prep: weight transposes + edge histogram (cnt pre-zeroed by memset) ----------
__global__ void k_prep(const float* __restrict__ Wn, unsigned short* __restrict__ WnT,
                       const float* __restrict__ W1, unsigned short* __restrict__ W1T,
                       const float* __restrict__ W2, unsigned short* __restrict__ W2T,
                       const int* __restrict__ dst, int* __restrict__ cnt, int E) {
    const int gs = gridDim.x * blockDim.x;
    const int tid = blockIdx.x * blockDim.x + threadIdx.x;
    for (int i = tid; i < 256 * 128; i += gs) {   // WnT[col][k], col=head*64+d
        int col = i >> 7, k = i & 127;
        int head = col >> 6, d = col & 63;
        WnT[i] = f2bf(Wn[(size_t)head * 8192 + (size_t)k * 64 + d]);
    }
    for (int i = tid; i < 256 * 256; i += gs) {   // W1T[n][k] = W1[k][n]
        int n = i >> 8, k = i & 255;
        W1T[i] = f2bf(W1[(size_t)k * 256 + n]);
    }
    for (int i = tid; i < 128 * 256; i += gs) {   // W2T[n][k] = W2[k][n]
        int n = i >> 8, k = i & 255;
        W2T[i] = f2bf(W2[(size_t)k * 128 + n]);
    }
    for (int i = tid; i < E; i += gs) atomicAdd(cnt + dst[i], 1);  // histogram
}

// ---------- K3a/b/c: two-level exclusive scan (proven version) ----------
__global__ __launch_bounds__(256) void k_scan1(
    const int* __restrict__ cnt, int* __restrict__ rowptr, int* __restrict__ bsum, int N) {
    __shared__ int wtot[4];
    const int lane = threadIdx.x & 63, wave = threadIdx.x >> 6;
    const int i = blockIdx.x * 256 + threadIdx.x;
    int v = (i < N) ? cnt[i] : 0;
    int x = v;
    for (int off = 1; off < 64; off <<= 1) {
        int y = __shfl_up(x, off, 64);
        if (lane >= off) x += y;
    }
    if (lane == 63) wtot[wave] = x;
    __syncthreads();
    int wo = 0;
    for (int wv = 0; wv < wave; ++wv) wo += wtot[wv];
    if (i < N) rowptr[i] = wo + x - v;
    if (threadIdx.x == 255) bsum[blockIdx.x] = wo + x;
}
__global__ void k_scan2(int* __restrict__ bsum, int nb) {
    const int lane = threadIdx.x;
    int carry = 0;
    for (int base = 0; base < nb; base += 64) {
        int i = base + lane;
        int v = (i < nb) ? bsum[i] : 0;
        int x = v;
        for (int off = 1; off < 64; off <<= 1) {
            int y = __shfl_up(x, off, 64);
            if (lane >= off) x += y;
        }
        if (i < nb) bsum[i] = carry + x - v;
        carry += __shfl(x, 63, 64);
    }
}
__global__ void k_scan3(int* __restrict__ rowptr, const int* __restrict__ bsum,
                        int* __restrict__ wcnt, int N, int E) {
    int i = blockIdx.x * blockDim.x + threadIdx.x;
    if (i < N) {
        int v = rowptr[i] + bsum[i >> 8];
        rowptr[i] = v;
        wcnt[i] = v;
    }
    if (i == N) rowptr[N] = E;
}

// ---------- K_scatter: src ids into CSR order ----------
__global__ void k_scatter(const int* __restrict__ src, const int* __restrict__ dst,
                          int* __restrict__ wcnt, int* __restrict__ esrc, int E) {
    int e = blockIdx.x * blockDim.x + threadIdx.x;
    if (e < E) {
        int pos = atomicAdd(wcnt + dst[e], 1);
        esrc[pos] = src[e];
    }
}

// ---------- K_agg: per-dst gather-aggregate -> concat (bf16) ----------
// One dst row per wave (fine-grained balance). 16 edge slots/lane-group; the
// esrc + s_src loads for block b+1 are issued before block b's inner loop so
// the 2-deep dependent chain overlaps the 16 row-gathers.
__global__ __launch_bounds__(256) void k_agg(
    const float* __restrict__ s_src, const float* __restrict__ s_dst,
    const unsigned short* __restrict__ h_bf,
    const int* __restrict__ rowptr, const int* __restrict__ esrc,
    unsigned short* __restrict__ concat, int N) {
    const int t = threadIdx.x;
    const int lane = t & 63;
    const int wave = t >> 6;
    const int n = blockIdx.x * 4 + wave;
    if (n >= N) return;

    const int head = lane >> 4;
    const int c0 = lane << 2;
    const int eslot = lane & 15;
    const int hsel = lane & 48;

    const int beg = rowptr[n], end = rowptr[n + 1];
    const float sdst = s_dst[n * 4 + head];
    float num0 = 0, num1 = 0, num2 = 0, num3 = 0, den = 0;

    // prefetch block 0 meta
    int sid = 0;
    float sv = 0.0f;
    if (beg < end && eslot < end - beg) {
        sid = esrc[beg + eslot];
        sv = s_src[sid * 4 + head];
    }

    for (int base = beg; base < end; base += 16) {
        const int nn = end - base;
        // prefetch next block meta (overlaps inner loop below)
        int sidn = 0;
        float svn = 0.0f;
        if (base + 16 < end) {
            if (eslot < end - (base + 16)) {
                sidn = esrc[base + 16 + eslot];
                svn = s_src[sidn * 4 + head];
            }
        }
        float my_ex = 0.0f;
        if (eslot < nn) {
            float v = sv + sdst;
            v = fmaxf(v, LEAKY * v);
            my_ex = __expf(v);
        }
#pragma unroll
        for (int e = 0; e < 16; ++e) {
            float ex = __shfl(my_ex, hsel | e, 64);
            int s    = __shfl(sid, e, 64);
            ushort4 hv = *(const ushort4*)(h_bf + (size_t)s * 256 + c0);
            num0 += ex * bf2f(hv.x);
            num1 += ex * bf2f(hv.y);
            num2 += ex * bf2f(hv.z);
            num3 += ex * bf2f(hv.w);
            den  += ex;
        }
        sid = sidn; sv = svn;
    }

    const float inv = 1.0f / (den > 0.0f ? den : 1.0f);
    ushort4 o;
    o.x = f2bf(relu_nan(num0 * inv));
    o.y = f2bf(relu_nan(num1 * inv));
    o.z = f2bf(relu_nan(num2 * inv));
    o.w = f2bf(relu_nan(num3 * inv));
    *(ushort4*)(concat + (size_t)n * 256 + c0) = o;
}

// ---------- K_gemm: tiled MFMA GEMM, templated on K / epilogue / A-dtype ----------
// MODE 0: bf16 out, no bias; FUSED score epilogue (each wave owns one head's 64 cols)
//         AF32=true: A is fp32, converted to bf16 during reg-staged LDS write.
// MODE 1: bf16 out, +bias, relu     (MLP layer 1 -> hidden)
// MODE 2: fp32 out, +bias           (MLP layer 2 -> final)
template <int K, int MODE, bool AF32>
__global__ __launch_bounds__(256) void k_gemm(
    const void* __restrict__ A, const unsigned short* __restrict__ BT,
    const float* __restrict__ bias, unsigned short* __restrict__ Cb,
    float* __restrict__ Cf, int N, int ldout,
    const float* __restrict__ asrc, const float* __restrict__ adst,
    float* __restrict__ s_src, float* __restrict__ s_dst) {
    __shared__ unsigned short As[128 * 32];
    __shared__ unsigned short Bs[128 * 32];
    const int t = threadIdx.x;
    const int lane = t & 63;
    const int w = t >> 6;
    const int wy = w >> 1, wx = w & 1;
    const int lm = lane & 15, quad = lane >> 4;
    const int row0 = blockIdx.x * 128;
    const int n0 = blockIdx.y * 128;
    const int srow = lane >> 2;
    const int sk = (lane & 3) * 8;

    floatx4 acc[4][4];
    if (MODE == 0) {
#pragma unroll
        for (int mi = 0; mi < 4; ++mi)
#pragma unroll
            for (int ni = 0; ni < 4; ++ni) acc[mi][ni] = (floatx4){0, 0, 0, 0};
    } else {
#pragma unroll
        for (int ni = 0; ni < 4; ++ni) {
            float b = bias[n0 + wx * 64 + ni * 16 + lm];
#pragma unroll
            for (int mi = 0; mi < 4; ++mi) acc[mi][ni] = (floatx4){b, b, b, b};
        }
    }

    for (int k0 = 0; k0 < K; k0 += 32) {
#pragma unroll
        for (int p = 0; p < 2; ++p) {
            int tr = (p * 4 + w) * 16 + srow;
            int ga = row0 + tr; if (ga >= N) ga = N - 1;   // clamp (stores guarded)
            if (AF32) {
                const float* Af = (const float*)A;
                float4 v0 = *(const float4*)(Af + (size_t)ga * K + k0 + sk);
                float4 v1 = *(const float4*)(Af + (size_t)ga * K + k0 + sk + 4);
                short8 pk;
                pk[0] = (short)f2bf(v0.x); pk[1] = (short)f2bf(v0.y);
                pk[2] = (short)f2bf(v0.z); pk[3] = (short)f2bf(v0.w);
                pk[4] = (short)f2bf(v1.x); pk[5] = (short)f2bf(v1.y);
                pk[6] = (short)f2bf(v1.z); pk[7] = (short)f2bf(v1.w);
                *(short8*)(As + (size_t)tr * 32 + sk) = pk;
            } else {
                gload_lds16((const unsigned short*)A + (size_t)ga * K + k0 + sk,
                            (char*)As + (size_t)tr * 64 + sk * 2);
            }
            gload_lds16(BT + (size_t)(n0 + tr) * K + k0 + sk,
                        (char*)Bs + (size_t)tr * 64 + sk * 2);
        }
        __syncthreads();
        short8 af[4], bfr[4];
#pragma unroll
        for (int mi = 0; mi < 4; ++mi)
            af[mi] = *(const short8*)(As + (size_t)(wy * 64 + mi * 16 + lm) * 32 + quad * 8);
#pragma unroll
        for (int ni = 0; ni < 4; ++ni)
            bfr[ni] = *(const short8*)(Bs + (size_t)(wx * 64 + ni * 16 + lm) * 32 + quad * 8);
#pragma unroll
        for (int mi = 0; mi < 4; ++mi)
#pragma unroll
            for (int ni = 0; ni < 4; ++ni)
                acc[mi][ni] = __builtin_amdgcn_mfma_f32_16x16x32_bf16(af[mi], bfr[ni], acc[mi][ni], 0, 0, 0);
        __syncthreads();
    }

#pragma unroll
    for (int mi = 0; mi < 4; ++mi)
#pragma unroll
        for (int ni = 0; ni < 4; ++ni)
#pragma unroll
            for (int q = 0; q < 4; ++q) {
                int r = row0 + wy * 64 + mi * 16 + quad * 4 + q;
                int c = n0 + wx * 64 + ni * 16 + lm;
                if (r < N) {
                    if (MODE == 0)      Cb[(size_t)r * ldout + c] = f2bf(acc[mi][ni][q]);
                    else if (MODE == 1) Cb[(size_t)r * ldout + c] = f2bf(relu_nan(acc[mi][ni][q]));
                    else                Cf[(size_t)r * ldout + c] = acc[mi][ni][q];
                }
            }

    if (MODE == 0) {
        // fused attention-score epilogue: this wave's 64 cols = one full head
        const int head = blockIdx.y * 2 + wx;
        float as[4], ad[4];
#pragma unroll
        for (int ni = 0; ni < 4; ++ni) {
            int d = ni * 16 + lm;
            as[ni] = asrc[head * 64 + d];
            ad[ni] = adst[head * 64 + d];
        }
#pragma unroll
        for (int mi = 0; mi < 4; ++mi)
#pragma unroll
            for (int q = 0; q < 4; ++q) {
                float ps = acc[mi][0][q] * as[0] + acc[mi][1][q] * as[1]
                         + acc[mi][2][q] * as[2] + acc[mi][3][q] * as[3];
                float pd = acc[mi][0][q] * ad[0] + acc[mi][1][q] * ad[1]
                         + acc[mi][2][q] * ad[2] + acc[mi][3][q] * ad[3];
#pragma unroll
                for (int m = 1; m < 16; m <<= 1) {
                    ps += __shfl_xor(ps, m, 64);
                    pd += __shfl_xor(pd, m, 64);
                }
                if (lm == 0) {
                    int r = row0 + wy * 64 + mi * 16 + quad * 4 + q;
                    if (r < N) {
                        s_src[r * 4 + head] = ps;
                        s_dst[r * 4 + head] = pd;
                    }
                }
            }
    }
}

extern "C" void kernel_launch(void* const* d_in, const int* in_sizes, int n_in,
                              void* d_out, int out_size, void* d_ws, size_t ws_size,
                              hipStream_t stream) {
    const float* X    = (const float*)d_in[0];
    const int* src    = (const int*)d_in[1];
    const int* dst    = (const int*)d_in[2];
    const float* Wn   = (const float*)d_in[3];
    const float* Asrc = (const float*)d_in[4];
    const float* Adst = (const float*)d_in[5];
    const float* W1   = (const float*)d_in[6];
    const float* b1   = (const float*)d_in[7];
    const float* W2   = (const float*)d_in[8];
    const float* b2   = (const float*)d_in[9];
    float* out = (float*)d_out;

    const int N = in_sizes[0] / 128;   // 50000
    const int E = in_sizes[1];         // 800000
    const int NBS = (N + 255) / 256;   // scan blocks
    const int NR = (N + 127) / 128;    // GEMM row tiles

    // ws layout (16B-aligned offsets), ~31 MB.
    size_t off = 0;
    char* w = (char*)d_ws;
    unsigned short* h_bf = (unsigned short*)(w + off); off += (size_t)N * 256 * 2;
    float* s_src = (float*)(w + off);                  off += (size_t)N * 4 * 4;
    float* s_dst = (float*)(w + off);                  off += (size_t)N * 4 * 4;
    int* cnt     = (int*)(w + off);                    off += (size_t)N * 4;
    int* rowptr  = (int*)(w + off);                    off += ((size_t)(N + 1) * 4 + 15) & ~15ull;
    int* wcnt    = (int*)(w + off);                    off += (size_t)N * 4;
    int* bsum    = (int*)(w + off);                    off += ((size_t)NBS * 4 + 15) & ~15ull;
    int* esrc    = (int*)(w + off);                    off += (size_t)E * 4;
    unsigned short* W1T = (unsigned short*)(w + off);  off += 256 * 256 * 2;
    unsigned short* W2T = (unsigned short*)(w + off);  off += 128 * 256 * 2;
    unsigned short* WnT = (unsigned short*)(w + off);  off += 256 * 128 * 2;
    const size_t required = off;

    if (ws_size < required) {
        k_fill<<<dim3((out_size + 255) / 256), dim3(256), 0, stream>>>(
            out, (float)(ws_size >> 20), out_size);
        return;
    }

    // d_out staging: concat (bf16 [N,256]) from k_agg -> consumed by gemm1;
    // then final fp32 out overwrites it (concat dead after gemm1).
    unsigned short* concat = (unsigned short*)d_out;

    hipMemsetAsync(cnt, 0, (size_t)N * sizeof(int), stream);
    k_prep<<<dim3(2048), dim3(256), 0, stream>>>(Wn, WnT, W1, W1T, W2, W2T, dst, cnt, E);
    // h = bf16(X) @ WnT (MFMA, A staged from fp32) + fused s_src/s_dst epilogue
    k_gemm<128, 0, true><<<dim3(NR, 2), dim3(256), 0, stream>>>(
        X, WnT, nullptr, h_bf, nullptr, N, 256, Asrc, Adst, s_src, s_dst);
    k_scan1<<<dim3(NBS), dim3(256), 0, stream>>>(cnt, rowptr, bsum, N);
    k_scan2<<<dim3(1), dim3(64), 0, stream>>>(bsum, NBS);
    k_scan3<<<dim3((N + 256) / 256), dim3(256), 0, stream>>>(rowptr, bsum, wcnt, N, E);
    k_scatter<<<dim3((E + 255) / 256), dim3(256), 0, stream>>>(src, dst, wcnt, esrc, E);
    k_agg<<<dim3((N + 3) / 4), dim3(256), 0, stream>>>(s_src, s_dst, h_bf, rowptr, esrc,
                                                       concat, N);
    // layer 1: hidden = relu(concat @ W1 + b1) -> h_bf (h is dead after k_agg)
    k_gemm<256, 1, false><<<dim3(NR, 2), dim3(256), 0, stream>>>(
        concat, W1T, b1, h_bf, nullptr, N, 256, nullptr, nullptr, nullptr, nullptr);
    // layer 2: out = hidden @ W2 + b2 -> fp32 into d_out
    k_gemm<256, 2, false><<<dim3(NR, 1), dim3(256), 0, stream>>>(
        h_bf, W2T, b2, nullptr, out, N, 128, nullptr, nullptr, nullptr, nullptr);
}

// Round 6
// 298.105 us; speedup vs baseline: 1.1705x; 1.0061x over previous
//
#include <hip/hip_runtime.h>

#define LEAKY 0.2f

typedef __attribute__((ext_vector_type(8))) short short8;   // 8 bf16 (MFMA A/B frag)
typedef __attribute__((ext_vector_type(4))) float floatx4;  // MFMA C/D frag
typedef __attribute__((ext_vector_type(8))) unsigned short ushort8_t;

__device__ __forceinline__ float bf2f(unsigned short u) {
    return __uint_as_float(((unsigned)u) << 16);
}
__device__ __forceinline__ unsigned short f2bf(float f) {
    unsigned u = __float_as_uint(f);
    unsigned r = (u + 0x7fffu + ((u >> 16) & 1u)) >> 16;  // RNE
    return (unsigned short)r;
}
__device__ __forceinline__ float relu_nan(float v) { return v < 0.0f ? 0.0f : v; }

// async global->LDS, 16 B per lane (dest = wave-uniform base + lane*16)
__device__ __forceinline__ void gload_lds16(const void* g, void* l) {
    __builtin_amdgcn_global_load_lds((const __attribute__((address_space(1))) void*)g,
                                     (__attribute__((address_space(3))) void*)l, 16, 0, 0);
}

// ---------- K_fill (ws-too-small diagnosis) ----------
__global__ void k_fill(float* __restrict__ p, float val, int n) {
    int i = blockIdx.x * blockDim.x + threadIdx.x;
    if (i < n) p[i] = val;
}

// ---------- K_prep: weight transposes + edge histogram (cnt pre-zeroed by memset) ----------
__global__ void k_prep(const float* __restrict__ Wn, unsigned short* __restrict__ WnT,
                       const float* __restrict__ W1, unsigned short* __restrict__ W1T,
                       const float* __restrict__ W2, unsigned short* __restrict__ W2T,
                       const int* __restrict__ dst, int* __restrict__ cnt, int E) {
    const int gs = gridDim.x * blockDim.x;
    const int tid = blockIdx.x * blockDim.x + threadIdx.x;
    for (int i = tid; i < 256 * 128; i += gs) {   // WnT[col][k], col=head*64+d
        int col = i >> 7, k = i & 127;
        int head = col >> 6, d = col & 63;
        WnT[i] = f2bf(Wn[(size_t)head * 8192 + (size_t)k * 64 + d]);
    }
    for (int i = tid; i < 256 * 256; i += gs) {   // W1T[n][k] = W1[k][n]
        int n = i >> 8, k = i & 255;
        W1T[i] = f2bf(W1[(size_t)k * 256 + n]);
    }
    for (int i = tid; i < 128 * 256; i += gs) {   // W2T[n][k] = W2[k][n]
        int n = i >> 8, k = i & 255;
        W2T[i] = f2bf(W2[(size_t)k * 128 + n]);
    }
    for (int i = tid; i < E; i += gs) atomicAdd(cnt + dst[i], 1);  // histogram
}

// ---------- K3a/b/c: two-level exclusive scan (proven version) ----------
__global__ __launch_bounds__(256) void k_scan1(
    const int* __restrict__ cnt, int* __restrict__ rowptr, int* __restrict__ bsum, int N) {
    __shared__ int wtot[4];
    const int lane = threadIdx.x & 63, wave = threadIdx.x >> 6;
    const int i = blockIdx.x * 256 + threadIdx.x;
    int v = (i < N) ? cnt[i] : 0;
    int x = v;
    for (int off = 1; off < 64; off <<= 1) {
        int y = __shfl_up(x, off, 64);
        if (lane >= off) x += y;
    }
    if (lane == 63) wtot[wave] = x;
    __syncthreads();
    int wo = 0;
    for (int wv = 0; wv < wave; ++wv) wo += wtot[wv];
    if (i < N) rowptr[i] = wo + x - v;
    if (threadIdx.x == 255) bsum[blockIdx.x] = wo + x;
}
__global__ void k_scan2(int* __restrict__ bsum, int nb) {
    const int lane = threadIdx.x;
    int carry = 0;
    for (int base = 0; base < nb; base += 64) {
        int i = base + lane;
        int v = (i < nb) ? bsum[i] : 0;
        int x = v;
        for (int off = 1; off < 64; off <<= 1) {
            int y = __shfl_up(x, off, 64);
            if (lane >= off) x += y;
        }
        if (i < nb) bsum[i] = carry + x - v;
        carry += __shfl(x, 63, 64);
    }
}
__global__ void k_scan3(int* __restrict__ rowptr, const int* __restrict__ bsum,
                        int* __restrict__ wcnt, int N, int E) {
    int i = blockIdx.x * blockDim.x + threadIdx.x;
    if (i < N) {
        int v = rowptr[i] + bsum[i >> 8];
        rowptr[i] = v;
        wcnt[i] = v;
    }
    if (i == N) rowptr[N] = E;
}

// ---------- K_scatter: src ids into CSR order ----------
__global__ void k_scatter(const int* __restrict__ src, const int* __restrict__ dst,
                          int* __restrict__ wcnt, int* __restrict__ esrc, int E) {
    int e = blockIdx.x * blockDim.x + threadIdx.x;
    if (e < E) {
        int pos = atomicAdd(wcnt + dst[e], 1);
        esrc[pos] = src[e];
    }
}

// ---------- K_agg: per-dst gather-aggregate -> concat (bf16) ----------
// One dst row per wave (fine-grained balance); next-block esrc/s_src meta
// prefetched before the inner loop so the dependent chain overlaps the gathers.
__global__ __launch_bounds__(256) void k_agg(
    const float* __restrict__ s_src, const float* __restrict__ s_dst,
    const unsigned short* __restrict__ h_bf,
    const int* __restrict__ rowptr, const int* __restrict__ esrc,
    unsigned short* __restrict__ concat, int N) {
    const int t = threadIdx.x;
    const int lane = t & 63;
    const int wave = t >> 6;
    const int n = blockIdx.x * 4 + wave;
    if (n >= N) return;

    const int head = lane >> 4;
    const int c0 = lane << 2;
    const int eslot = lane & 15;
    const int hsel = lane & 48;

    const int beg = rowptr[n], end = rowptr[n + 1];
    const float sdst = s_dst[n * 4 + head];
    float num0 = 0, num1 = 0, num2 = 0, num3 = 0, den = 0;

    // prefetch block 0 meta
    int sid = 0;
    float sv = 0.0f;
    if (beg < end && eslot < end - beg) {
        sid = esrc[beg + eslot];
        sv = s_src[sid * 4 + head];
    }

    for (int base = beg; base < end; base += 16) {
        const int nn = end - base;
        // prefetch next block meta (overlaps inner loop below)
        int sidn = 0;
        float svn = 0.0f;
        if (base + 16 < end) {
            if (eslot < end - (base + 16)) {
                sidn = esrc[base + 16 + eslot];
                svn = s_src[sidn * 4 + head];
            }
        }
        float my_ex = 0.0f;
        if (eslot < nn) {
            float v = sv + sdst;
            v = fmaxf(v, LEAKY * v);
            my_ex = __expf(v);
        }
#pragma unroll
        for (int e = 0; e < 16; ++e) {
            float ex = __shfl(my_ex, hsel | e, 64);
            int s    = __shfl(sid, e, 64);
            ushort4 hv = *(const ushort4*)(h_bf + (size_t)s * 256 + c0);
            num0 += ex * bf2f(hv.x);
            num1 += ex * bf2f(hv.y);
            num2 += ex * bf2f(hv.z);
            num3 += ex * bf2f(hv.w);
            den  += ex;
        }
        sid = sidn; sv = svn;
    }

    const float inv = 1.0f / (den > 0.0f ? den : 1.0f);
    ushort4 o;
    o.x = f2bf(relu_nan(num0 * inv));
    o.y = f2bf(relu_nan(num1 * inv));
    o.z = f2bf(relu_nan(num2 * inv));
    o.w = f2bf(relu_nan(num3 * inv));
    *(ushort4*)(concat + (size_t)n * 256 + c0) = o;
}

// ---------- K_gemm0: h = bf16(X) @ WnT, fused attention-score epilogue ----------
// A is fp32 X, converted to bf16 during reg-staged LDS write. Each wave owns
// one head's 64 cols for the score epilogue.
__global__ __launch_bounds__(256) void k_gemm0(
    const float* __restrict__ A, const unsigned short* __restrict__ BT,
    unsigned short* __restrict__ Cb, int N,
    const float* __restrict__ asrc, const float* __restrict__ adst,
    float* __restrict__ s_src, float* __restrict__ s_dst) {
    __shared__ unsigned short As[128 * 32];
    __shared__ unsigned short Bs[128 * 32];
    const int t = threadIdx.x;
    const int lane = t & 63;
    const int w = t >> 6;
    const int wy = w >> 1, wx = w & 1;
    const int lm = lane & 15, quad = lane >> 4;
    const int row0 = blockIdx.x * 128;
    const int n0 = blockIdx.y * 128;
    const int srow = lane >> 2;
    const int sk = (lane & 3) * 8;

    floatx4 acc[4][4];
#pragma unroll
    for (int mi = 0; mi < 4; ++mi)
#pragma unroll
        for (int ni = 0; ni < 4; ++ni) acc[mi][ni] = (floatx4){0, 0, 0, 0};

    for (int k0 = 0; k0 < 128; k0 += 32) {
#pragma unroll
        for (int p = 0; p < 2; ++p) {
            int tr = (p * 4 + w) * 16 + srow;
            int ga = row0 + tr; if (ga >= N) ga = N - 1;   // clamp (stores guarded)
            float4 v0 = *(const float4*)(A + (size_t)ga * 128 + k0 + sk);
            float4 v1 = *(const float4*)(A + (size_t)ga * 128 + k0 + sk + 4);
            short8 pk;
            pk[0] = (short)f2bf(v0.x); pk[1] = (short)f2bf(v0.y);
            pk[2] = (short)f2bf(v0.z); pk[3] = (short)f2bf(v0.w);
            pk[4] = (short)f2bf(v1.x); pk[5] = (short)f2bf(v1.y);
            pk[6] = (short)f2bf(v1.z); pk[7] = (short)f2bf(v1.w);
            *(short8*)(As + (size_t)tr * 32 + sk) = pk;
            gload_lds16(BT + (size_t)(n0 + tr) * 128 + k0 + sk,
                        (char*)Bs + (size_t)tr * 64 + sk * 2);
        }
        __syncthreads();
        short8 af[4], bfr[4];
#pragma unroll
        for (int mi = 0; mi < 4; ++mi)
            af[mi] = *(const short8*)(As + (size_t)(wy * 64 + mi * 16 + lm) * 32 + quad * 8);
#pragma unroll
        for (int ni = 0; ni < 4; ++ni)
            bfr[ni] = *(const short8*)(Bs + (size_t)(wx * 64 + ni * 16 + lm) * 32 + quad * 8);
#pragma unroll
        for (int mi = 0; mi < 4; ++mi)
#pragma unroll
            for (int ni = 0; ni < 4; ++ni)
                acc[mi][ni] = __builtin_amdgcn_mfma_f32_16x16x32_bf16(af[mi], bfr[ni], acc[mi][ni], 0, 0, 0);
        __syncthreads();
    }

#pragma unroll
    for (int mi = 0; mi < 4; ++mi)
#pragma unroll
        for (int ni = 0; ni < 4; ++ni)
#pragma unroll
            for (int q = 0; q < 4; ++q) {
                int r = row0 + wy * 64 + mi * 16 + quad * 4 + q;
                int c = n0 + wx * 64 + ni * 16 + lm;
                if (r < N) Cb[(size_t)r * 256 + c] = f2bf(acc[mi][ni][q]);
            }

    // fused attention-score epilogue: this wave's 64 cols = one full head
    const int head = blockIdx.y * 2 + wx;
    float as[4], ad[4];
#pragma unroll
    for (int ni = 0; ni < 4; ++ni) {
        int d = ni * 16 + lm;
        as[ni] = asrc[head * 64 + d];
        ad[ni] = adst[head * 64 + d];
    }
#pragma unroll
    for (int mi = 0; mi < 4; ++mi)
#pragma unroll
        for (int q = 0; q < 4; ++q) {
            float ps = acc[mi][0][q] * as[0] + acc[mi][1][q] * as[1]
                     + acc[mi][2][q] * as[2] + acc[mi][3][q] * as[3];
            float pd = acc[mi][0][q] * ad[0] + acc[mi][1][q] * ad[1]
                     + acc[mi][2][q] * ad[2] + acc[mi][3][q] * ad[3];
#pragma unroll
            for (int m = 1; m < 16; m <<= 1) {
                ps += __shfl_xor(ps, m, 64);
                pd += __shfl_xor(pd, m, 64);
            }
            if (lm == 0) {
                int r = row0 + wy * 64 + mi * 16 + quad * 4 + q;
                if (r < N) {
                    s_src[r * 4 + head] = ps;
                    s_dst[r * 4 + head] = pd;
                }
            }
        }
}

// ---------- K_mlp: fused MLP  out = (relu(concat@W1+b1))@W2 + b2 ----------
// One block = 64 rows. Stage 1: hidden(64x256) in-register (waves split cols),
// relu -> bf16 -> LDS Hs[64][264] (+8 pad). Stage 2: Hs @ W2T -> out(64x128) f32.
// In-place safe: block reads exactly concat rows [r0,r0+64) (same d_out bytes
// it later writes as f32 out); clamp row N-1 lies in the last block's range.
__global__ __launch_bounds__(256) void k_mlp(
    const unsigned short* __restrict__ concat,   // [N][256] bf16 (in d_out)
    const unsigned short* __restrict__ W1T,      // [256][256] bf16 [n][k]
    const float* __restrict__ b1,
    const unsigned short* __restrict__ W2T,      // [128][256] bf16 [n][k]
    const float* __restrict__ b2,
    float* __restrict__ outp, int N) {           // [N][128] f32 (same bytes)
    __shared__ unsigned short As[64 * 32];       // 4 KB
    __shared__ unsigned short Bs[256 * 32];      // 16 KB (stage 2 reuses 8 KB)
    __shared__ unsigned short Hs[64 * 264];      // 33 KB (+8 pad per row)
    const int t = threadIdx.x;
    const int lane = t & 63;
    const int w = t >> 6;
    const int lm = lane & 15, quad = lane >> 4;
    const int row0 = blockIdx.x * 64;
    const int tr = t >> 2;          // 0..63
    const int sk = (t & 3) * 8;     // k-element offset

    // ---- stage 1: hidden = relu(concat @ W1 + b1), wave w owns cols w*64.. ----
    floatx4 acc[4][4];
#pragma unroll
    for (int ni = 0; ni < 4; ++ni) {
        float b = b1[w * 64 + ni * 16 + lm];
#pragma unroll
        for (int mi = 0; mi < 4; ++mi) acc[mi][ni] = (floatx4){b, b, b, b};
    }

    for (int k0 = 0; k0 < 256; k0 += 32) {
        {   // A: 64 rows x 32 k
            int ga = row0 + tr; if (ga >= N) ga = N - 1;
            gload_lds16(concat + (size_t)ga * 256 + k0 + sk,
                        (char*)As + (size_t)tr * 64 + sk * 2);
        }
#pragma unroll
        for (int p = 0; p < 4; ++p) {   // B: 256 rows of W1T
            int rn = p * 64 + tr;
            gload_lds16(W1T + (size_t)rn * 256 + k0 + sk,
                        (char*)Bs + (size_t)rn * 64 + sk * 2);
        }
        __syncthreads();
        short8 af[4], bfr[4];
#pragma unroll
        for (int mi = 0; mi < 4; ++mi)
            af[mi] = *(const short8*)(As + (size_t)(mi * 16 + lm) * 32 + quad * 8);
#pragma unroll
        for (int ni = 0; ni < 4; ++ni)
            bfr[ni] = *(const short8*)(Bs + (size_t)(w * 64 + ni * 16 + lm) * 32 + quad * 8);
#pragma unroll
        for (int mi = 0; mi < 4; ++mi)
#pragma unroll
            for (int ni = 0; ni < 4; ++ni)
                acc[mi][ni] = __builtin_amdgcn_mfma_f32_16x16x32_bf16(af[mi], bfr[ni], acc[mi][ni], 0, 0, 0);
        __syncthreads();
    }

    // hidden -> Hs (relu, bf16)
#pragma unroll
    for (int mi = 0; mi < 4; ++mi)
#pragma unroll
        for (int ni = 0; ni < 4; ++ni)
#pragma unroll
            for (int q = 0; q < 4; ++q) {
                int row = mi * 16 + quad * 4 + q;
                int col = w * 64 + ni * 16 + lm;
                Hs[row * 264 + col] = f2bf(relu_nan(acc[mi][ni][q]));
            }

    // ---- stage 2: out = Hs @ W2 + b2, wave w owns cols w*32.. ----
    floatx4 acc2[4][2];
#pragma unroll
    for (int ni = 0; ni < 2; ++ni) {
        float b = b2[w * 32 + ni * 16 + lm];
#pragma unroll
        for (int mi = 0; mi < 4; ++mi) acc2[mi][ni] = (floatx4){b, b, b, b};
    }

    for (int k0 = 0; k0 < 256; k0 += 32) {
#pragma unroll
        for (int p = 0; p < 2; ++p) {   // B: 128 rows of W2T
            int rn = p * 64 + tr;
            gload_lds16(W2T + (size_t)rn * 256 + k0 + sk,
                        (char*)Bs + (size_t)rn * 64 + sk * 2);
        }
        __syncthreads();   // Bs2 staged AND (k0==0) Hs writes visible to all waves
        short8 af[4], bfr[2];
#pragma unroll
        for (int mi = 0; mi < 4; ++mi)
            af[mi] = *(const short8*)(Hs + (size_t)(mi * 16 + lm) * 264 + k0 + quad * 8);
#pragma unroll
        for (int ni = 0; ni < 2; ++ni)
            bfr[ni] = *(const short8*)(Bs + (size_t)(w * 32 + ni * 16 + lm) * 32 + quad * 8);
#pragma unroll
        for (int mi = 0; mi < 4; ++mi)
#pragma unroll
            for (int ni = 0; ni < 2; ++ni)
                acc2[mi][ni] = __builtin_amdgcn_mfma_f32_16x16x32_bf16(af[mi], bfr[ni], acc2[mi][ni], 0, 0, 0);
        __syncthreads();
    }

#pragma unroll
    for (int mi = 0; mi < 4; ++mi)
#pragma unroll
        for (int ni = 0; ni < 2; ++ni)
#pragma unroll
            for (int q = 0; q < 4; ++q) {
                int r = row0 + mi * 16 + quad * 4 + q;
                int c = w * 32 + ni * 16 + lm;
                if (r < N) outp[(size_t)r * 128 + c] = acc2[mi][ni][q];
            }
}

extern "C" void kernel_launch(void* const* d_in, const int* in_sizes, int n_in,
                              void* d_out, int out_size, void* d_ws, size_t ws_size,
                              hipStream_t stream) {
    const float* X    = (const float*)d_in[0];
    const int* src    = (const int*)d_in[1];
    const int* dst    = (const int*)d_in[2];
    const float* Wn   = (const float*)d_in[3];
    const float* Asrc = (const float*)d_in[4];
    const float* Adst = (const float*)d_in[5];
    const float* W1   = (const float*)d_in[6];
    const float* b1   = (const float*)d_in[7];
    const float* W2   = (const float*)d_in[8];
    const float* b2   = (const float*)d_in[9];
    float* out = (float*)d_out;

    const int N = in_sizes[0] / 128;   // 50000
    const int E = in_sizes[1];         // 800000
    const int NBS = (N + 255) / 256;   // scan blocks
    const int NR = (N + 127) / 128;    // gemm0 row tiles
    const int NM = (N + 63) / 64;      // k_mlp row tiles

    // ws layout (16B-aligned offsets), ~31 MB.
    size_t off = 0;
    char* w = (char*)d_ws;
    unsigned short* h_bf = (unsigned short*)(w + off); off += (size_t)N * 256 * 2;
    float* s_src = (float*)(w + off);                  off += (size_t)N * 4 * 4;
    float* s_dst = (float*)(w + off);                  off += (size_t)N * 4 * 4;
    int* cnt     = (int*)(w + off);                    off += (size_t)N * 4;
    int* rowptr  = (int*)(w + off);                    off += ((size_t)(N + 1) * 4 + 15) & ~15ull;
    int* wcnt    = (int*)(w + off);                    off += (size_t)N * 4;
    int* bsum    = (int*)(w + off);                    off += ((size_t)NBS * 4 + 15) & ~15ull;
    int* esrc    = (int*)(w + off);                    off += (size_t)E * 4;
    unsigned short* W1T = (unsigned short*)(w + off);  off += 256 * 256 * 2;
    unsigned short* W2T = (unsigned short*)(w + off);  off += 128 * 256 * 2;
    unsigned short* WnT = (unsigned short*)(w + off);  off += 256 * 128 * 2;
    const size_t required = off;

    if (ws_size < required) {
        k_fill<<<dim3((out_size + 255) / 256), dim3(256), 0, stream>>>(
            out, (float)(ws_size >> 20), out_size);
        return;
    }

    // d_out staging: concat (bf16 [N,256]) from k_agg -> consumed in-place by k_mlp,
    // which overwrites the same bytes with the final fp32 out.
    unsigned short* concat = (unsigned short*)d_out;

    hipMemsetAsync(cnt, 0, (size_t)N * sizeof(int), stream);
    k_prep<<<dim3(2048), dim3(256), 0, stream>>>(Wn, WnT, W1, W1T, W2, W2T, dst, cnt, E);
    // h = bf16(X) @ WnT (MFMA, A staged from fp32) + fused s_src/s_dst epilogue
    k_gemm0<<<dim3(NR, 2), dim3(256), 0, stream>>>(
        X, WnT, h_bf, N, Asrc, Adst, s_src, s_dst);
    k_scan1<<<dim3(NBS), dim3(256), 0, stream>>>(cnt, rowptr, bsum, N);
    k_scan2<<<dim3(1), dim3(64), 0, stream>>>(bsum, NBS);
    k_scan3<<<dim3((N + 256) / 256), dim3(256), 0, stream>>>(rowptr, bsum, wcnt, N, E);
    k_scatter<<<dim3((E + 255) / 256), dim3(256), 0, stream>>>(src, dst, wcnt, esrc, E);
    k_agg<<<dim3((N + 3) / 4), dim3(256), 0, stream>>>(s_src, s_dst, h_bf, rowptr, esrc,
                                                       concat, N);
    // fused MLP: out = relu(concat @ W1 + b1) @ W2 + b2   (in-place in d_out)
    k_mlp<<<dim3(NM), dim3(256), 0, stream>>>(concat, W1T, b1, W2T, b2, out, N);
}